// Round 1
// 124.515 us; speedup vs baseline: 1.0028x; 1.0028x over previous
//
#include <hip/hip_runtime.h>

// CAN: per-sample 2-layer MLP, B=16384, N=50, D=16.
// R8: transposed-chain 16x16x16 MFMA. Key identity: for the K=16 shape the
// B-operand layout (lane: B[4q+j][n]) == C/D layout (lane: D[4q+r][n]), so
// computing y^T = W0^T x^T then z^T = W1^T y^T chains layer1's accumulator
// straight into layer2's B operand - NO inter-layer LDS transpose.
//   - x^T B-fragment = contiguous float4 per lane from GLOBAL (no x staging):
//     lane(q,n) reads x[t*16+n][4q..4q+3]; wave covers the 1KB tile exactly.
//   - Only param stage (544 f = 2176B) goes through LDS via global_load_lds.
//   - Output z^T layout = 4 consecutive floats of row n per lane ->
//     one global_store_dwordx4 per tile, fully coalesced 1KB/wave.
//   - LDS/block 22.5KB -> 9KB; __launch_bounds__(256,8) -> 32 waves/CU.

#define CAN_D 16
#define CAN_N 50
#define CAN_PSTRIDE 544
#define WAVES_PER_BLOCK 4
#define PSTAGE 2304          // 2*1024 + 256B tail piece (clamped-lane overflow pad)

typedef __attribute__((ext_vector_type(4))) short bf16x4;
typedef __attribute__((ext_vector_type(4))) float f32x4;
#define AS1 __attribute__((address_space(1)))
#define AS3 __attribute__((address_space(3)))

union BFrag { int i[2]; bf16x4 v; };

// RNE fp32->bf16, lo -> bits [15:0]
__device__ __forceinline__ int pack2(float lo, float hi) {
    unsigned short ua = __builtin_bit_cast(unsigned short, (__bf16)lo);
    unsigned short ub = __builtin_bit_cast(unsigned short, (__bf16)hi);
    return (int)((unsigned)ua | ((unsigned)ub << 16));
}

__device__ __forceinline__ f32x4 mfma16(bf16x4 a, bf16x4 b, f32x4 c) {
#if __has_builtin(__builtin_amdgcn_mfma_f32_16x16x16bf16_1k)
    return __builtin_amdgcn_mfma_f32_16x16x16bf16_1k(a, b, c, 0, 0, 0);
#else
    f32x4 d;
    asm volatile("s_nop 1\n\t"
                 "v_mfma_f32_16x16x16_bf16 %0, %1, %2, %3\n\t"
                 "s_nop 7\n\ts_nop 7"
                 : "=&v"(d) : "v"(a), "v"(b), "v"(c));
    return d;
#endif
}

__global__ __launch_bounds__(256, 8) void can_kernel(
    const float* __restrict__ user_emb,
    const float* __restrict__ item_emb,
    float* __restrict__ out, int B)
{
    __shared__ __align__(16) char smem[WAVES_PER_BLOCK * PSTAGE];

    const int wave = threadIdx.x >> 6;
    const int lane = threadIdx.x & 63;
    const int s = blockIdx.x * WAVES_PER_BLOCK + wave;
    const bool active = (s < B);

    char* pw = smem + wave * PSTAGE;

    if (active) {
        const float* gp = item_emb + (size_t)s * CAN_PSTRIDE;     // 544 f
        __builtin_amdgcn_global_load_lds((const AS1 void*)(gp + lane * 4),
                                         (AS3 void*)pw, 16, 0, 0);
        __builtin_amdgcn_global_load_lds((const AS1 void*)(gp + 256 + lane * 4),
                                         (AS3 void*)(pw + 1024), 16, 0, 0);
        int idx = 512 + lane; if (idx > 543) idx = 543;            // clamp tail
        __builtin_amdgcn_global_load_lds((const AS1 void*)(gp + idx),
                                         (AS3 void*)(pw + 2048), 4, 0, 0);
    }

    __syncthreads();    // drains vmcnt(0): DMA data visible in LDS
    if (!active) return;

    const int n    = lane & 15;     // output column = x row-within-tile
    const int quad = lane >> 4;
    const float* pf = (const float*)pw;

    // A-fragments of W^T for both layers: lane(q,n) holds W[k=4q+j][n], j=0..3.
    // (ds_read_b32 x8, 4-way bank alias across quads - ~free per m136.)
    BFrag w0, w1;
    {
        float t0[4], t1[4];
#pragma unroll
        for (int j = 0; j < 4; ++j) {
            t0[j] = pf[(4 * quad + j) * CAN_D + n];
            t1[j] = pf[272 + (4 * quad + j) * CAN_D + n];
        }
        w0.i[0] = pack2(t0[0], t0[1]); w0.i[1] = pack2(t0[2], t0[3]);
        w1.i[0] = pack2(t1[0], t1[1]); w1.i[1] = pack2(t1[2], t1[3]);
    }
    // Bias in transposed space: C-in[r] = b[4q+r] (one ds_read_b128 each).
    const f32x4 b0v = *(const f32x4*)(pf + 256 + 4 * quad);
    const f32x4 b1v = *(const f32x4*)(pf + 528 + 4 * quad);

    const float* gx = user_emb + (size_t)s * (CAN_N * CAN_D);     // 800 f
    float* ob = out + (size_t)s * (CAN_N * CAN_D);

#pragma unroll
    for (int t = 0; t < 4; ++t) {
        // x^T B-fragment: lane(q,n) = x[t*16+n][4q..4q+3], straight from global.
        int row = t * 16 + n;
        if (row > CAN_N - 1) row = CAN_N - 1;      // clamp; masked at store
        f32x4 xv = *(const f32x4*)(gx + row * CAN_D + 4 * quad);
        BFrag xb;
        xb.i[0] = pack2(xv[0], xv[1]);
        xb.i[1] = pack2(xv[2], xv[3]);

        // Layer 1: D1 = W0^T * x^T + b0  (lane holds y[n][4q+r])
        f32x4 d1 = mfma16(w0.v, xb.v, b0v);

        // relu + pack: D1 registers ARE the layer-2 B-fragment (layout identity)
        BFrag yb;
        yb.i[0] = pack2(fmaxf(d1[0], 0.0f), fmaxf(d1[1], 0.0f));
        yb.i[1] = pack2(fmaxf(d1[2], 0.0f), fmaxf(d1[3], 0.0f));

        // Layer 2: D2 = W1^T * y^T + b1  (lane holds z[n][4q+r])
        f32x4 d2 = mfma16(w1.v, yb.v, b1v);

        f32x4 r;
#pragma unroll
        for (int k = 0; k < 4; ++k) r[k] = fmaxf(d2[k], 0.0f);

        // Coalesced store: lane writes 16B of row t*16+n; wave covers 1KB tile.
        int orow = t * 16 + n;
        if (orow < CAN_N)
            *(f32x4*)(ob + orow * CAN_D + 4 * quad) = r;
    }
}

extern "C" void kernel_launch(void* const* d_in, const int* in_sizes, int n_in,
                              void* d_out, int out_size, void* d_ws, size_t ws_size,
                              hipStream_t stream) {
    const float* user_emb = (const float*)d_in[0];
    const float* item_emb = (const float*)d_in[1];
    float* out = (float*)d_out;

    const int B = in_sizes[0] / (CAN_N * CAN_D);   // 16384
    const int blocks = (B + WAVES_PER_BLOCK - 1) / WAVES_PER_BLOCK;
    can_kernel<<<blocks, 256, 0, stream>>>(user_emb, item_emb, out, B);
}